// Round 22
// baseline (115.534 us; speedup 1.0000x reference)
//
#include <hip/hip_runtime.h>

// PathGNNLayers: per-edge MLP + scatter-max GNN layer.
//   x:[N,32] f32, edge_index:[2,E] int32, edge_attr:[E,32] f32
//   W1:[96,64], b1:[64], W2:[64,32], b2:[32]
//   out[n] = max( x[n, -32:], max_{e: col[e]==n} MLP(x[row_e], x[col_e], ea[e]) )
//
// R22: LINEAR edge order + encoded global atomicMax. The CSR/bin machinery
// (3 launches + it randomized the 102MB ea stream) is deleted. R1/R2 showed
// the sign-split atomics added ~zero HBM traffic (R1's 12GB was spill).
//   prep:   out = encf(x) (residual/empty floor), x->bf16, weight shuffle
//   edge:   512 linear edges/block; ea fully coalesced NT stream; only the
//           3.2MB xbf row gathers are random (L2-resident, protected by NT);
//           MFMA MLP (mi-split), epilogue = branchless atomicMax(u32) on
//           monotone-encoded f32 (order-independent -> deterministic)
//   decode: out encf -> f32
// NOTE: no min-waves launch bound (R11: a VGPR cap spills -> 40MB scratch).

constexpr int XD   = 32;
constexpr int HID  = 64;
constexpr int OUTD = 32;
constexpr int BM   = 128;   // edges per MFMA tile
constexpr int EPT  = 512;   // edges per block (4 tiles)
constexpr int HSTR = 72;    // H LDS stride in bf16 units

typedef __attribute__((ext_vector_type(8)))  short    short8;
typedef __attribute__((ext_vector_type(4)))  float    f32x4;
typedef __attribute__((ext_vector_type(4)))  float    floatx4;

static __device__ __forceinline__ unsigned f2bf(float f) {
    union { float f; unsigned u; } x; x.f = f;
    unsigned r = x.u + 0x7fff + ((x.u >> 16) & 1);   // RNE; finite inputs
    return r >> 16;
}
// monotone f32<->u32 encoding: enc order == float order (finite values)
static __device__ __forceinline__ unsigned encf(float f) {
    unsigned u = __float_as_uint(f);
    return (u >> 31) ? ~u : (u | 0x80000000u);
}
static __device__ __forceinline__ float decf(unsigned k) {
    return __uint_as_float((k >> 31) ? (k & 0x7fffffffu) : ~k);
}

// ---- prep: out = encf(x), x->bf16 table, W1/W2 -> MFMA B-fragment order ----
__global__ __launch_bounds__(256) void prep(
    const float* __restrict__ x, unsigned* __restrict__ outE,
    unsigned* __restrict__ xbf,
    const float* __restrict__ W1, const float* __restrict__ W2,
    unsigned* __restrict__ w1s, unsigned* __restrict__ w2s,
    int total4, int total8)
{
    const int i = blockIdx.x * 256 + threadIdx.x;

    if (i < total4) {                      // out = encf(x), 4 floats/thread
        const float4 a = reinterpret_cast<const float4*>(x)[i];
        uint4 o;
        o.x = encf(a.x); o.y = encf(a.y); o.z = encf(a.z); o.w = encf(a.w);
        reinterpret_cast<uint4*>(outE)[i] = o;
    }

    if (i < total8) {                      // x (f32) -> xbf (bf16), 8 floats/thread
        const float4* src = reinterpret_cast<const float4*>(x) + (size_t)i * 2;
        float4 a = src[0], bb = src[1];
        uint4 o;
        o.x = f2bf(a.x)  | (f2bf(a.y)  << 16);
        o.y = f2bf(a.z)  | (f2bf(a.w)  << 16);
        o.z = f2bf(bb.x) | (f2bf(bb.y) << 16);
        o.w = f2bf(bb.z) | (f2bf(bb.w) << 16);
        reinterpret_cast<uint4*>(xbf)[i] = o;
    }

    // B-frag for tile (nt,ks): lane l holds B[k=ks*32+(l>>4)*8+j][col=nt*16+(l&15)]
    if (i < 768) {                         // W1: 4 nt x 3 ks x 64 lanes
        const int ti = i >> 6, lane = i & 63;
        const int nt = ti / 3, ks = ti % 3;
        const int col = nt * 16 + (lane & 15);
        const int k0  = ks * 32 + ((lane >> 4) << 3);
        unsigned o[4];
#pragma unroll
        for (int p = 0; p < 4; ++p)
            o[p] = f2bf(W1[(k0 + 2 * p) * HID + col]) |
                   (f2bf(W1[(k0 + 2 * p + 1) * HID + col]) << 16);
        reinterpret_cast<uint4*>(w1s)[i] = make_uint4(o[0], o[1], o[2], o[3]);
    } else if (i < 1024) {                 // W2: 2 nt x 2 ks x 64 lanes
        const int tt = i - 768;
        const int ti = tt >> 6, lane = tt & 63;
        const int nt = ti >> 1, ks = ti & 1;
        const int col = nt * 16 + (lane & 15);
        const int k0  = ks * 32 + ((lane >> 4) << 3);
        unsigned o[4];
#pragma unroll
        for (int p = 0; p < 4; ++p)
            o[p] = f2bf(W2[(k0 + 2 * p) * OUTD + col]) |
                   (f2bf(W2[(k0 + 2 * p + 1) * OUTD + col]) << 16);
        reinterpret_cast<uint4*>(w2s)[tt] = make_uint4(o[0], o[1], o[2], o[3]);
    }
}

// ---- edge MLP over linear edges + encoded atomicMax scatter ----
__global__ __launch_bounds__(256) void edge_mlp_atomic(
    const unsigned* __restrict__ xbf,   // [N][16] u32 = [N][32] bf16
    const int*      __restrict__ ei,    // [2][E]
    const float*    __restrict__ ea,    // [E][32] f32
    const unsigned* __restrict__ w1s,   // [12][64] x 16B frags (L1-hot)
    const unsigned* __restrict__ w2s,   // [4][64] x 16B frags
    const float*    __restrict__ b1,
    const float*    __restrict__ b2,
    unsigned*       __restrict__ outE,  // [N][32] encoded f32 max
    int n_edges)
{
    __shared__ alignas(16) unsigned short Hlds[4 * 16 * HSTR];  // 16 rows/wave

    const int t    = threadIdx.x;
    const int lane = t & 63;
    const int wave = t >> 6;
    const int base = blockIdx.x * EPT;

    // per-lane weight fragment pointers (compiler hoists invariant loads)
    const unsigned* w1p = w1s + (size_t)lane * 4;
    const unsigned* w2p = w2s + (size_t)lane * 4;

    float bb1[4];
#pragma unroll
    for (int nt = 0; nt < 4; ++nt) bb1[nt] = b1[nt * 16 + (lane & 15)];
    float bb2[2];
#pragma unroll
    for (int nt = 0; nt < 2; ++nt) bb2[nt] = b2[nt * 16 + (lane & 15)];

    const int koff  = lane >> 4;          // 0..3: 16B/32B slice of a row
    const int hbase = wave * 16;          // this wave's private H stripe

#pragma unroll 1
    for (int tile = 0; tile < EPT / BM; ++tile) {
        const int tbase = base + tile * BM;
        if (tbase >= n_edges) break;

        // lanes 0-31: load endpoint ids for slot (wave*32 + lane), coalesced
        unsigned qx = 0u;
        if (lane < 32) {
            int e = tbase + wave * 32 + lane;
            if (e >= n_edges) e = n_edges - 1;      // duplicate pad; max-idempotent
            const unsigned row = (unsigned)ei[e];
            const unsigned col = (unsigned)ei[n_edges + e];
            qx = (row << 16) | col;                 // ids < 65536
        }

        // ---- mi-split: fully process each 16-row half-tile
#pragma unroll
        for (int mi = 0; mi < 2; ++mi) {
            const int s = mi * 16 + (lane & 15);    // slot in wave stripe
            const unsigned rcp = (unsigned)__shfl((int)qx, s, 64);
            const unsigned idR = rcp >> 16;
            const unsigned idC = rcp & 0xffffu;

            int e_slot = tbase + wave * 32 + s;     // my slot's edge (linear!)
            if (e_slot >= n_edges) e_slot = n_edges - 1;

            // A-frags: endpoints gathered from L2-resident xbf;
            // ea fragment COALESCED (wave covers 16 consecutive 128B rows), NT
            const short8 aR = *reinterpret_cast<const short8*>(
                xbf + (size_t)idR * 16 + koff * 4);
            const short8 aC = *reinterpret_cast<const short8*>(
                xbf + (size_t)idC * 16 + koff * 4);
            const floatx4* ep = reinterpret_cast<const floatx4*>(
                ea + (size_t)e_slot * 32 + koff * 8);
            const floatx4 e0 = __builtin_nontemporal_load(ep);
            const floatx4 e1 = __builtin_nontemporal_load(ep + 1);
            union { uint4 u; short8 s8; } ae;
            ae.u.x = f2bf(e0.x) | (f2bf(e0.y) << 16);
            ae.u.y = f2bf(e0.z) | (f2bf(e0.w) << 16);
            ae.u.z = f2bf(e1.x) | (f2bf(e1.y) << 16);
            ae.u.w = f2bf(e1.z) | (f2bf(e1.w) << 16);

            f32x4 acc1[4];
#pragma unroll
            for (int nt = 0; nt < 4; ++nt) acc1[nt] = (f32x4){0.f, 0.f, 0.f, 0.f};
#pragma unroll
            for (int nt = 0; nt < 4; ++nt) {
                const short8 wA = *reinterpret_cast<const short8*>(w1p + (size_t)(nt * 3 + 0) * 256);
                const short8 wB = *reinterpret_cast<const short8*>(w1p + (size_t)(nt * 3 + 1) * 256);
                const short8 wE = *reinterpret_cast<const short8*>(w1p + (size_t)(nt * 3 + 2) * 256);
                acc1[nt] = __builtin_amdgcn_mfma_f32_16x16x32_bf16(aR,    wA, acc1[nt], 0, 0, 0);
                acc1[nt] = __builtin_amdgcn_mfma_f32_16x16x32_bf16(aC,    wB, acc1[nt], 0, 0, 0);
                acc1[nt] = __builtin_amdgcn_mfma_f32_16x16x32_bf16(ae.s8, wE, acc1[nt], 0, 0, 0);
            }

            // bias + ReLU -> H (bf16) into this wave's 16-row stripe.
            // C layout: col=lane&15, row=(lane>>4)*4+r. Wave-private: no barrier.
#pragma unroll
            for (int nt = 0; nt < 4; ++nt)
#pragma unroll
                for (int r = 0; r < 4; ++r) {
                    const float h = fmaxf(acc1[nt][r] + bb1[nt], 0.0f);
                    Hlds[(hbase + ((lane >> 4) << 2) + r) * HSTR + nt * 16 + (lane & 15)] =
                        (unsigned short)f2bf(h);
                }

            // layer 2: [16x64] @ [64x32]
            f32x4 acc2[2];
#pragma unroll
            for (int nt = 0; nt < 2; ++nt) acc2[nt] = (f32x4){0.f, 0.f, 0.f, 0.f};
#pragma unroll
            for (int ks = 0; ks < 2; ++ks) {
                const short8 hfrag = *reinterpret_cast<const short8*>(
                    &Hlds[(hbase + (lane & 15)) * HSTR + ks * 32 + ((lane >> 4) << 3)]);
#pragma unroll
                for (int nt = 0; nt < 2; ++nt) {
                    const short8 wF = *reinterpret_cast<const short8*>(w2p + (size_t)(nt * 2 + ks) * 256);
                    acc2[nt] = __builtin_amdgcn_mfma_f32_16x16x32_bf16(hfrag, wF, acc2[nt], 0, 0, 0);
                }
            }

            // epilogue: bias + branchless encoded atomicMax into out
#pragma unroll
            for (int r = 0; r < 4; ++r) {
                const int rowl = mi * 16 + ((lane >> 4) << 2) + r;   // slot in stripe
                const unsigned rcp2 = (unsigned)__shfl((int)qx, rowl, 64);
                const unsigned col  = rcp2 & 0xffffu;
#pragma unroll
                for (int nt = 0; nt < 2; ++nt) {
                    const float val = acc2[nt][r] + bb2[nt];
                    atomicMax(outE + (size_t)col * OUTD + nt * 16 + (lane & 15), encf(val));
                }
            }
        }
    }
}

// ---- decode: out encf(u32) -> f32, in place ----
__global__ __launch_bounds__(256) void decode_out(unsigned* __restrict__ outE, int total4)
{
    const int i = blockIdx.x * 256 + threadIdx.x;
    if (i < total4) {
        uint4 v = reinterpret_cast<const uint4*>(outE)[i];
        float4 o;
        o.x = decf(v.x); o.y = decf(v.y); o.z = decf(v.z); o.w = decf(v.w);
        reinterpret_cast<float4*>(outE)[i] = o;
    }
}

extern "C" void kernel_launch(void* const* d_in, const int* in_sizes, int n_in,
                              void* d_out, int out_size, void* d_ws, size_t ws_size,
                              hipStream_t stream)
{
    const float* x  = (const float*)d_in[0];
    const int*   ei = (const int*)  d_in[1];
    const float* ea = (const float*)d_in[2];
    const float* W1 = (const float*)d_in[3];
    const float* b1 = (const float*)d_in[4];
    const float* W2 = (const float*)d_in[5];
    const float* b2 = (const float*)d_in[6];
    unsigned* outE = (unsigned*)d_out;

    const int n_nodes = in_sizes[0] / XD;
    const int n_edges = in_sizes[2] / 32;

    // ws: xbf[N*16 u32] | w1s | w2s
    size_t off_b = 0;
    unsigned* xbf = (unsigned*)((char*)d_ws + off_b); off_b += (size_t)n_nodes * 16 * 4;
    unsigned* w1s = (unsigned*)((char*)d_ws + off_b); off_b += 768 * 16;
    unsigned* w2s = (unsigned*)((char*)d_ws + off_b);

    const int total4 = n_nodes * OUTD / 4;   // out elements / 4
    const int total8 = n_nodes * XD / 8;
    const int prep_grid = (max(total4, max(total8, 1024)) + 255) / 256;
    const int edge_grid = (n_edges + EPT - 1) / EPT;     // 1563

    prep<<<prep_grid, 256, 0, stream>>>(x, outE, xbf, W1, W2, w1s, w2s, total4, total8);
    edge_mlp_atomic<<<edge_grid, 256, 0, stream>>>(
        xbf, ei, ea, w1s, w2s, b1, b2, outE, n_edges);
    decode_out<<<(total4 + 255) / 256, 256, 0, stream>>>(outE, total4);
}